// Round 1
// baseline (3035.746 us; speedup 1.0000x reference)
//
#include <hip/hip_runtime.h>

// Net_87814901334404: B=512, CI=3, HW=28, K=7, C=1024, NH=16, L=12, T=17, M=B*T=8704
// All d_in are fp32 (per reference dtypes); d_out fp32 [512,3,7,119].
// Strategy: bf16-MFMA GEMMs (m97 structure: 128x128 tile, BK=32, global_load_lds w=16),
// fp32 residual stream h, bf16 activations/weights for matmuls.

typedef unsigned short u16;
typedef short bfrag8 __attribute__((ext_vector_type(8)));
typedef float facc4 __attribute__((ext_vector_type(4)));

__device__ __forceinline__ u16 f2bf(float f) {
  union { float f; unsigned u; } x; x.f = f;
  unsigned r = x.u + 0x7fffu + ((x.u >> 16) & 1u);   // round-to-nearest-even
  return (u16)(r >> 16);
}
__device__ __forceinline__ float bf2f(u16 h) {
  union { unsigned u; float f; } x; x.u = ((unsigned)h) << 16;
  return x.f;
}

// ---------------------------------------------------------------------------
// GEMM: out[m,n] = sum_k A[m,k] * B[n,k]  (B given row-major [N][K], i.e. W in out = A @ W^T)
// A,B bf16; acc fp32 via mfma_f32_16x16x32_bf16.
// MODE 0: fp32 out = acc (+bias);  MODE 1: bf16 out = acc (+bias);  MODE 2: fp32 out += acc (+bias)
// blockIdx.z selects B0/B1/B2 and offsets out by z*zstride (QKV batching).
// Verified layouts (learn_hip m89/m91/m120): A/B frag: idx=lane&15, k=(lane>>4)*8+j;
// C/D: col=lane&15, row=(lane>>4)*4+reg.
// ---------------------------------------------------------------------------
template <int MODE>
__global__ __launch_bounds__(256) void gemm_bt(
    const u16* __restrict__ A, int lda,
    const u16* __restrict__ B0, const u16* __restrict__ B1, const u16* __restrict__ B2,
    int ldb, int K,
    void* __restrict__ outp, long long zstride, int ldo,
    const float* __restrict__ bias)
{
  __shared__ __align__(16) u16 As[128 * 32];
  __shared__ __align__(16) u16 Bs[128 * 32];

  const int m0 = blockIdx.x * 128;
  const int n0 = blockIdx.y * 128;
  const int z  = blockIdx.z;
  const u16* __restrict__ B = (z == 0) ? B0 : ((z == 1) ? B1 : B2);

  const int tid  = threadIdx.x;
  const int wave = tid >> 6;
  const int lane = tid & 63;
  const int wm   = (wave >> 1) * 64;
  const int wn   = (wave & 1) * 64;
  const int lrow = lane & 15;
  const int lquad = lane >> 4;

  facc4 acc[4][4] = {};

  // staging chunk ids (16B = 8 bf16 per chunk; tile = 512 chunks; 256 threads x 2)
  const int c0 = tid;        const int r0 = c0 >> 2; const int k0c = (c0 & 3) << 3;
  const int c1 = tid + 256;  const int r1 = c1 >> 2; const int k1c = (c1 & 3) << 3;

  for (int k0 = 0; k0 < K; k0 += 32) {
    const u16* ga0 = A + (long long)(m0 + r0) * lda + (k0 + k0c);
    const u16* ga1 = A + (long long)(m0 + r1) * lda + (k0 + k1c);
    const u16* gb0 = B + (long long)(n0 + r0) * ldb + (k0 + k0c);
    const u16* gb1 = B + (long long)(n0 + r1) * ldb + (k0 + k1c);
    __builtin_amdgcn_global_load_lds((const __attribute__((address_space(1))) void*)ga0,
                                     (__attribute__((address_space(3))) void*)(As + c0 * 8), 16, 0, 0);
    __builtin_amdgcn_global_load_lds((const __attribute__((address_space(1))) void*)ga1,
                                     (__attribute__((address_space(3))) void*)(As + c1 * 8), 16, 0, 0);
    __builtin_amdgcn_global_load_lds((const __attribute__((address_space(1))) void*)gb0,
                                     (__attribute__((address_space(3))) void*)(Bs + c0 * 8), 16, 0, 0);
    __builtin_amdgcn_global_load_lds((const __attribute__((address_space(1))) void*)gb1,
                                     (__attribute__((address_space(3))) void*)(Bs + c1 * 8), 16, 0, 0);
    __syncthreads();   // drains vmcnt -> LDS tiles complete

    bfrag8 af[4], bfr[4];
#pragma unroll
    for (int im = 0; im < 4; ++im)
      af[im] = *(const bfrag8*)(As + (wm + im * 16 + lrow) * 32 + lquad * 8);
#pragma unroll
    for (int in = 0; in < 4; ++in)
      bfr[in] = *(const bfrag8*)(Bs + (wn + in * 16 + lrow) * 32 + lquad * 8);
#pragma unroll
    for (int im = 0; im < 4; ++im)
#pragma unroll
      for (int in = 0; in < 4; ++in)
        acc[im][in] = __builtin_amdgcn_mfma_f32_16x16x32_bf16(af[im], bfr[in], acc[im][in], 0, 0, 0);
    __syncthreads();   // before next iteration overwrites LDS
  }

#pragma unroll
  for (int in = 0; in < 4; ++in) {
    const int col = n0 + wn + in * 16 + lrow;
    const float bb = bias ? bias[col] : 0.0f;
#pragma unroll
    for (int im = 0; im < 4; ++im) {
#pragma unroll
      for (int r = 0; r < 4; ++r) {
        const int row = m0 + wm + im * 16 + lquad * 4 + r;
        const long long off = (long long)row * ldo + col;
        const float v = acc[im][in][r] + bb;
        if (MODE == 0)       ((float*)outp)[off] = v;
        else if (MODE == 1)  (((u16*)outp) + zstride * z)[off] = f2bf(v);
        else                 ((float*)outp)[off] += v;
      }
    }
  }
}

// ---------------------------------------------------------------------------
// LayerNorm over C=1024: reads fp32 h row, writes bf16 normalized row.
// ---------------------------------------------------------------------------
__global__ __launch_bounds__(256) void ln_kernel(
    const float* __restrict__ h, const float* __restrict__ w,
    const float* __restrict__ b, u16* __restrict__ out)
{
  const long long row = blockIdx.x;
  const float* __restrict__ x = h + row * 1024;
  const int t = threadIdx.x;
  float v0 = x[t], v1 = x[t + 256], v2 = x[t + 512], v3 = x[t + 768];
  float s = v0 + v1 + v2 + v3;
  float q = v0 * v0 + v1 * v1 + v2 * v2 + v3 * v3;
  for (int o = 32; o > 0; o >>= 1) { s += __shfl_down(s, o); q += __shfl_down(q, o); }
  __shared__ float ss[4], sq[4];
  const int wave = t >> 6, lane = t & 63;
  if (lane == 0) { ss[wave] = s; sq[wave] = q; }
  __syncthreads();
  const float st = ss[0] + ss[1] + ss[2] + ss[3];
  const float qt = sq[0] + sq[1] + sq[2] + sq[3];
  const float mean = st * (1.0f / 1024.0f);
  const float var = qt * (1.0f / 1024.0f) - mean * mean;
  const float inv = rsqrtf(var + 1e-5f);
  u16* o2 = out + row * 1024;
  o2[t]       = f2bf((v0 - mean) * inv * w[t]       + b[t]);
  o2[t + 256] = f2bf((v1 - mean) * inv * w[t + 256] + b[t + 256]);
  o2[t + 512] = f2bf((v2 - mean) * inv * w[t + 512] + b[t + 512]);
  o2[t + 768] = f2bf((v3 - mean) * inv * w[t + 768] + b[t + 768]);
}

// ---------------------------------------------------------------------------
// Causal attention, T=17, hd=64. One block per (batch, head). h += attn output.
// QKV: bf16 [3][8704][1024], rows (b*17+t), cols (head*64+d).
// ---------------------------------------------------------------------------
__global__ __launch_bounds__(256) void attn_kernel(const u16* __restrict__ QKV,
                                                   float* __restrict__ h)
{
  const int blk = blockIdx.x;          // 0..8191
  const int b = blk >> 4, head = blk & 15;
  __shared__ float qs[17][64], ks[17][64], vs[17][64];
  __shared__ float sc[17][20];
  const long long base = (long long)b * 17 * 1024 + head * 64;
  const u16* Q  = QKV;
  const u16* Kp = QKV + 8912896LL;       // 8704*1024
  const u16* V  = QKV + 17825792LL;

  for (int i = threadIdx.x; i < 17 * 64; i += 256) {
    const int t = i >> 6, d = i & 63;
    const long long off = base + (long long)t * 1024 + d;
    qs[t][d] = bf2f(Q[off]); ks[t][d] = bf2f(Kp[off]); vs[t][d] = bf2f(V[off]);
  }
  __syncthreads();

  for (int i = threadIdx.x; i < 289; i += 256) {
    const int tq = i / 17, tk = i % 17;
    float a = 0.0f;
    if (tk <= tq) {
#pragma unroll
      for (int d = 0; d < 64; ++d) a += qs[tq][d] * ks[tk][d];
      a *= 0.125f;                     // 1/sqrt(64)
    }
    sc[tq][tk] = a;
  }
  __syncthreads();

  if (threadIdx.x < 17) {
    const int tq = threadIdx.x;
    float m = -1e30f;
    for (int tk = 0; tk <= tq; ++tk) m = fmaxf(m, sc[tq][tk]);
    float s = 0.0f;
    for (int tk = 0; tk <= tq; ++tk) { const float e = __expf(sc[tq][tk] - m); sc[tq][tk] = e; s += e; }
    const float inv = 1.0f / s;
    for (int tk = 0; tk <= tq; ++tk) sc[tq][tk] *= inv;
  }
  __syncthreads();

  for (int i = threadIdx.x; i < 17 * 64; i += 256) {
    const int tq = i >> 6, d = i & 63;
    float a = 0.0f;
    for (int tk = 0; tk <= tq; ++tk) a += sc[tq][tk] * vs[tk][d];
    h[base + (long long)tq * 1024 + d] += a;   // exclusive owner of this slice
  }
}

// ---------------------------------------------------------------------------
// Build patch matrix P bf16 [8704][160]: row n=(b*17+t); t=0 thumb (2x2 avg at
// rows/cols 4p+1..4p+2 — jax bilinear half-pixel, scale 4 -> frac 0.5/0.5),
// t=1+s patch; cols 147..159 zero-pad.
// ---------------------------------------------------------------------------
__global__ void build_p(const float* __restrict__ x, u16* __restrict__ P)
{
  const int n = blockIdx.x;
  const int j = threadIdx.x;
  if (j >= 160) return;
  const int b = n / 17, t = n % 17;
  float val = 0.0f;
  if (j < 147) {
    const int c = j / 49, rem = j % 49, p = rem / 7, q = rem % 7;
    const float* xb = x + (long long)(b * 3 + c) * 784;
    if (t == 0) {
      const int r = 4 * p + 1, cc = 4 * q + 1;
      val = 0.25f * (xb[r * 28 + cc] + xb[r * 28 + cc + 1] +
                     xb[(r + 1) * 28 + cc] + xb[(r + 1) * 28 + cc + 1]);
    } else {
      const int s = t - 1, ii = s >> 2, jj = s & 3;
      val = xb[(7 * ii + p) * 28 + 7 * jj + q];
    }
  }
  P[(long long)n * 160 + j] = f2bf(val);
}

// conv_w fp32 [1024][147] -> Wc bf16 [1024][160] (zero-pad K) and
// cw2 bf16 [256][1024]: cw2[j][c] = conv_w[c*147+j], rows 147..255 zero.
__global__ __launch_bounds__(256) void cvt_conv(const float* __restrict__ cw,
                                                u16* __restrict__ Wc, u16* __restrict__ cw2)
{
  const int i = blockIdx.x * 256 + threadIdx.x;   // grid covers 163840 + 262144
  if (i < 163840) {
    const int d = i / 160, j = i % 160;
    Wc[i] = (j < 147) ? f2bf(cw[d * 147 + j]) : (u16)0;
  } else {
    const int i2 = i - 163840;
    if (i2 < 262144) {
      const int j = i2 / 1024, c = i2 % 1024;
      cw2[i2] = (j < 147) ? f2bf(cw[c * 147 + j]) : (u16)0;
    }
  }
}

// per-layer weight cast: wq,wk,wv -> wb3[3][1M], mlp -> wmb[1M]. grid 16384x256 exact.
__global__ __launch_bounds__(256) void cvt4(const float* __restrict__ a0, const float* __restrict__ a1,
                                            const float* __restrict__ a2, const float* __restrict__ a3,
                                            u16* __restrict__ o3, u16* __restrict__ om)
{
  const int i = blockIdx.x * 256 + threadIdx.x;
  const int which = i >> 20, off = i & 1048575;
  const float* src = (which == 0) ? a0 : (which == 1) ? a1 : (which == 2) ? a2 : a3;
  const float v = src[off];
  if (which < 3) o3[which * 1048576 + off] = f2bf(v);
  else           om[off] = f2bf(v);
}

__global__ __launch_bounds__(256) void cvtN(const float* __restrict__ in, u16* __restrict__ out, int n)
{
  const int i = blockIdx.x * 256 + threadIdx.x;
  if (i < n) out[i] = f2bf(in[i]);
}

// temp fp32 [8704][256] (cols j=d*49+hk*7+wk, rows n=b*17+s) -> out [b][d][hk][s*7+wk]
__global__ __launch_bounds__(256) void scatter_out(const float* __restrict__ temp, float* __restrict__ out)
{
  const int i = blockIdx.x * 256 + threadIdx.x;   // 4998*256 = 1,279,488 exact
  if (i >= 1279488) return;
  const int wk = i % 7;
  const int r  = i / 7;
  const int s  = r % 17;
  const int r2 = r / 17;
  const int hk = r2 % 7;
  const int r3 = r2 / 7;
  const int d  = r3 % 3;
  const int b  = r3 / 3;
  out[i] = temp[(long long)(b * 17 + s) * 256 + d * 49 + hk * 7 + wk];
}

// ---------------------------------------------------------------------------
extern "C" void kernel_launch(void* const* d_in, const int* in_sizes, int n_in,
                              void* d_out, int out_size, void* d_ws, size_t ws_size,
                              hipStream_t stream)
{
  const float* x     = (const float*)d_in[0];
  const float* convw = (const float*)d_in[1];
  const float* ln1w  = (const float*)d_in[2];
  const float* ln1b  = (const float*)d_in[3];
  const float* wq    = (const float*)d_in[4];
  const float* wk    = (const float*)d_in[5];
  const float* wv    = (const float*)d_in[6];
  const float* ln2w  = (const float*)d_in[7];
  const float* ln2b  = (const float*)d_in[8];
  const float* mlpw  = (const float*)d_in[9];
  const float* mlpb  = (const float*)d_in[10];
  const float* outw  = (const float*)d_in[11];
  const float* outb  = (const float*)d_in[12];
  // d_in[13] = head_num (16, hard-coded)

  char* w = (char*)d_ws;
  float* h    = (float*)(w);                 // 35,651,584 B  (also reused as decode temp)
  u16*  Abuf  = (u16*)(w + 35651584);        // 17,825,792 B
  u16*  QKV   = (u16*)(w + 53477376);        // 53,477,376 B  (also holds logits bf16)
  u16*  wb3   = (u16*)(w + 106954752);       //  6,291,456 B
  u16*  wmb   = (u16*)(w + 113246208);       //  2,097,152 B
  u16*  Wc    = (u16*)(w + 115343360);       //    327,680 B
  u16*  cw2   = (u16*)(w + 115671040);       //    524,288 B
  u16*  P     = (u16*)(w + 116195328);       //  2,785,280 B  -> total 118,980,608 B
  if (ws_size < 118980608ULL) return;

  // ---- embed ----
  cvt_conv<<<1664, 256, 0, stream>>>(convw, Wc, cw2);
  build_p<<<8704, 192, 0, stream>>>(x, P);
  gemm_bt<0><<<dim3(68, 8, 1), 256, 0, stream>>>(P, 160, Wc, Wc, Wc, 160, 160,
                                                 (void*)h, 0LL, 1024, nullptr);
  // ---- layers ----
  for (int l = 0; l < 12; ++l) {
    const size_t wo = (size_t)l * 1048576;
    cvt4<<<16384, 256, 0, stream>>>(wq + wo, wk + wo, wv + wo, mlpw + wo, wb3, wmb);
    ln_kernel<<<8704, 256, 0, stream>>>(h, ln1w + l * 1024, ln1b + l * 1024, Abuf);
    gemm_bt<1><<<dim3(68, 8, 3), 256, 0, stream>>>(Abuf, 1024, wb3, wb3 + 1048576, wb3 + 2097152,
                                                   1024, 1024, (void*)QKV, 8912896LL, 1024, nullptr);
    attn_kernel<<<8192, 256, 0, stream>>>(QKV, h);
    ln_kernel<<<8704, 256, 0, stream>>>(h, ln2w + l * 1024, ln2b + l * 1024, Abuf);
    gemm_bt<2><<<dim3(68, 8, 1), 256, 0, stream>>>(Abuf, 1024, wmb, wmb, wmb,
                                                   1024, 1024, (void*)h, 0LL, 1024, mlpb + l * 1024);
  }
  // ---- head: logits = h @ out_w^T + out_b ----
  cvtN<<<34816, 256, 0, stream>>>(h, Abuf, 8912896);
  cvtN<<<4096, 256, 0, stream>>>(outw, wmb, 1048576);
  gemm_bt<1><<<dim3(68, 8, 1), 256, 0, stream>>>(Abuf, 1024, wmb, wmb, wmb,
                                                 1024, 1024, (void*)QKV, 0LL, 1024, outb);
  // ---- decode: temp[n, j] = sum_c logits[n,c] * conv_w[c, j] ----
  gemm_bt<0><<<dim3(68, 2, 1), 256, 0, stream>>>(QKV, 1024, cw2, cw2, cw2,
                                                 1024, 1024, (void*)h, 0LL, 256, nullptr);
  scatter_out<<<4998, 256, 0, stream>>>(h, (float*)d_out);
}